// Round 3
// baseline (260.741 us; speedup 1.0000x reference)
//
#include <hip/hip_runtime.h>
#include <cstdint>
#include <cstddef>

typedef unsigned long long ull;

#define KTOP   1000
#define CAP    4096      // candidate gather capacity per (b,c)
#define HBITS  14
#define HSHIFT (32 - HBITS)
#define NB2    512       // histogram window: top-14-bit bins [BLO, BLO+NB2)
#define BLO    3584      // window floor = 3584<<18 = 3.05e-5; all scores >= cth=0.05 land in-window
#define ROWS   1024      // padded rank capacity (>= KTOP)
#define WORDS  16        // 1024 / 64 keep-mask words
#define HCHUNK 64        // score chunks per (b,c) for the LDS histogram kernel
#define GSTAGE 4096      // gather LDS staging capacity (>= per-block chunk)

// ---------------- Kernel 1: softmax scores + hist/cnt zeroing ----------------
__global__ void decode_kernel(const float* __restrict__ conf,
                              float* __restrict__ scores,   // [B*Cfg][P]
                              unsigned* __restrict__ histz, // hist+cnt region to zero
                              int histW,
                              int B, int C, int P) {
#pragma clang fp contract(off)
    int t = blockIdx.x * blockDim.x + threadIdx.x;

    for (int i = t; i < histW; i += gridDim.x * blockDim.x) histz[i] = 0u;

    if (t >= B * P) return;
    int b = t / P;
    int p = t - b * P;

    float x[8];
    float m = -INFINITY;
    for (int c = 0; c < C; ++c) {
        x[c] = conf[((size_t)b * C + c) * P + p];
        m = fmaxf(m, x[c]);
    }
    float sum = 0.f;
    for (int c = 0; c < C; ++c) {
        x[c] = expf(x[c] - m);
        sum += x[c];
    }
    for (int c = 1; c < C; ++c) {
        float v = x[c] / sum;
        int bc = b * (C - 1) + (c - 1);
        scores[(size_t)bc * P + p] = v;
    }
}

// ---------------- Kernel 2: windowed LDS score histogram ----------------
__global__ void __launch_bounds__(256)
hist_kernel(const float* __restrict__ scores,
            const float* __restrict__ cthp,
            unsigned* __restrict__ hist,     // [NBC][NB2]
            int P) {
    __shared__ unsigned sh[NB2 / 2];         // 1 KB (16-bit packed counters)
    int bc  = blockIdx.x;
    int tid = threadIdx.x;
    float cth = *cthp;

    sh[tid] = 0u;
    __syncthreads();

    int chunk = (P + gridDim.y - 1) / gridDim.y;
    int lo = blockIdx.y * chunk;
    int hi = lo + chunk; if (hi > P) hi = P;
    const float* s = scores + (size_t)bc * P;
    for (int p = lo + tid; p < hi; p += 256) {
        float v = s[p];
        if (v >= cth) {
            int bl = (int)(__float_as_uint(v) >> HSHIFT) - BLO;
            if (bl < 0) bl = 0;
            atomicAdd(&sh[bl >> 1], (bl & 1) ? 65536u : 1u);
        }
    }
    __syncthreads();

    unsigned* h = hist + (size_t)bc * NB2;
    unsigned v = sh[tid];
    if (v & 0xFFFFu)  atomicAdd(&h[2 * tid],     v & 0xFFFFu);
    if (v >> 16)      atomicAdd(&h[2 * tid + 1], v >> 16);
}

// ---------------- Kernel 3: inline pivot + single-pass gather ----------------
__global__ void __launch_bounds__(256)
gather_kernel(const float* __restrict__ scores,
              const unsigned* __restrict__ hist,
              unsigned* __restrict__ pivot,
              unsigned* __restrict__ cnt,
              ull* __restrict__ cand,
              const float* __restrict__ cthp, int P) {
    __shared__ ull stage[GSTAGE];            // 32 KB
    __shared__ unsigned T[256];
    __shared__ unsigned s_pv, l_cnt, s_base;
    int bc = blockIdx.x;
    int tid  = threadIdx.x;
    int lane = tid & 63;
    const float* s = scores + (size_t)bc * P;
    float cth = *cthp;

    // ---- pivot: suffix scan over the 512-bin window ----
    const unsigned* h = hist + (size_t)bc * NB2;
    unsigned s0 = h[2 * tid], s1 = h[2 * tid + 1];
    T[tid] = s0 + s1;
    if (tid == 0) { s_pv = 0u; l_cnt = 0u; }
    __syncthreads();
    for (int d = 1; d < 256; d <<= 1) {
        unsigned add = (tid + d < 256) ? T[tid + d] : 0u;
        __syncthreads();
        T[tid] += add;
        __syncthreads();
    }
    unsigned Tt = T[tid];
    unsigned Tn = (tid + 1 < 256) ? T[tid + 1] : 0u;
    if (Tt >= (unsigned)KTOP && Tn < (unsigned)KTOP) {
        unsigned pl = (Tn + s1 >= (unsigned)KTOP) ? (2u * tid + 1u) : (2u * tid);
        s_pv = pl + (unsigned)BLO;
    }
    __syncthreads();
    unsigned pv = s_pv;
    if (pv <= (unsigned)BLO) pv = 0u;        // fallback: take all >= cth
    if (blockIdx.y == 0 && tid == 0) pivot[bc] = pv;

    // ---- single-pass gather: ballot-aggregated LDS staging, one global atomic ----
    int nchunk = gridDim.y;
    int chunk = (P + nchunk - 1) / nchunk;   // <= GSTAGE by launcher construction
    int lo = blockIdx.y * chunk;
    int hi = lo + chunk; if (hi > P) hi = P;

    for (int p0 = lo; p0 < hi; p0 += 256) {
        int p = p0 + tid;
        bool q = false; unsigned k = 0u;
        if (p < hi) {
            float v = s[p];
            k = __float_as_uint(v);
            q = (v >= cth) && ((k >> HSHIFT) >= pv);
        }
        ull mb = __ballot(q);
        if (mb) {
            unsigned wbase = 0u;
            if (lane == 0) wbase = atomicAdd(&l_cnt, (unsigned)__popcll(mb));
            wbase = (unsigned)__shfl((int)wbase, 0);
            if (q) {
                unsigned pos = wbase + (unsigned)__popcll(mb & ((1ull << lane) - 1ull));
                stage[pos] = ((ull)k << 32) | (unsigned)(~(unsigned)p);
            }
        }
    }
    __syncthreads();

    unsigned tot = l_cnt;
    if (tid == 0) s_base = tot ? atomicAdd(&cnt[bc], tot) : 0u;
    __syncthreads();
    unsigned base = s_base;
    ull* cb = cand + (size_t)bc * CAP;
    for (unsigned i = tid; i < tot; i += 256) {
        unsigned off = base + i;
        if (off < CAP) cb[off] = stage[i];
    }
}

// ---------------- Kernel 4: fused refine + rank-scatter + streaming NMS + pack ----------------
// Replaces sort/mask/reduce_pack. Keys are unique (low 32 bits = ~p), so
// rank = #{keys > mine} is a permutation -> direct scatter, no bitonic (0 barriers
// vs 55). The NMS mask never exists in memory: chunks of 64 ranks are processed in
// order; "suppressed by previously-kept" is recomputed from LDS SoA boxes gated by
// finalized keep words; the 64x64 diagonal block feeds the group-pipelined serial
// greedy (wave 0). Everything LDS-resident (~78 KB), 1 block per (b,c).
__global__ void __launch_bounds__(1024)
nms_kernel(const ull* __restrict__ cand,
           const unsigned* __restrict__ cnt,
           const unsigned* __restrict__ pivot,
           const float* __restrict__ loc,
           const float* __restrict__ prior,
           const float* __restrict__ nthp,
           float* __restrict__ out,
           int P, int Cfg) {
#pragma clang fp contract(off)
    int bc  = blockIdx.x;
    int b   = bc / Cfg;
    int tid = threadIdx.x;
    int wv   = tid >> 6;
    int lane = tid & 63;

    __shared__ ull      sbuf[CAP];        // 32 KB candidate keys
    __shared__ unsigned h2[1024];         // 4 KB refine histogram / suffix sums
    __shared__ float sx1[ROWS], sy1[ROWS], sx2[ROWS], sy2[ROWS], sar[ROWS]; // 20 KB SoA boxes
    __shared__ float rowsL[KTOP * 5];     // ~20 KB (score,cx,cy,w,h per rank)
    __shared__ ull      Dm[64];           // diagonal 64x64 bit-matrix
    __shared__ ull      keepw[WORDS];
    __shared__ unsigned supArr[64];
    __shared__ unsigned s_hi, s_spv, s_m2, s_pos;
    __shared__ unsigned pref[WORDS + 1];

    float nth = *nthp;
    int M = (int)cnt[bc]; if (M > CAP) M = CAP;
    int nsel = M < KTOP ? M : KTOP;

    for (int i = tid; i < M; i += 1024)
        sbuf[i] = cand[(size_t)bc * CAP + i];
    for (int i = tid; i < ROWS; i += 1024) {           // clean slots >= nsel
        sx1[i] = 0.f; sy1[i] = 0.f; sx2[i] = 0.f; sy2[i] = 0.f; sar[i] = 0.f;
    }
    if (tid < WORDS) keepw[tid] = 0ull;
    __syncthreads();

    // ---- refine: cut M (<=4096) to Meff (~KTOP) via 10-bit sub-bin histogram ----
    int Meff = M;
    if (M > 1024) {
        unsigned pv = pivot[bc];
        h2[tid] = 0u;
        if (tid == 0) { s_hi = 0u; s_pos = 0u; s_spv = 0u; s_m2 = (unsigned)M; }
        __syncthreads();
        for (int i = tid; i < M; i += 1024) {
            unsigned sb32 = (unsigned)(sbuf[i] >> 32);
            if ((sb32 >> HSHIFT) > pv) atomicAdd(&s_hi, 1u);
            else atomicAdd(&h2[(sb32 >> 8) & 1023u], 1u);   // bin == pv (gather guarantee)
        }
        __syncthreads();
        unsigned hicnt = s_hi;               // < KTOP by pivot construction
        for (int d = 1; d < 1024; d <<= 1) { // in-place Hillis-Steele suffix sum
            unsigned add = (tid + d < 1024) ? h2[tid + d] : 0u;
            __syncthreads();
            h2[tid] += add;
            __syncthreads();
        }
        unsigned A  = hicnt + h2[tid];
        unsigned Bv = hicnt + ((tid + 1 < 1024) ? h2[tid + 1] : 0u);
        if (A >= (unsigned)KTOP && Bv < (unsigned)KTOP) { s_spv = (unsigned)tid; s_m2 = A; }
        __syncthreads();
        unsigned thr24 = ((unsigned)pv << 10) | s_spv;      // top-24-bit threshold
        Meff = (int)s_m2;
        ull my[4];
        #pragma unroll
        for (int j = 0; j < 4; ++j) { int i = tid + (j << 10); my[j] = (i < M) ? sbuf[i] : 0ull; }
        __syncthreads();
        #pragma unroll
        for (int j = 0; j < 4; ++j) {
            int i = tid + (j << 10);
            if (i < M && (unsigned)(my[j] >> 40) >= thr24) {
                unsigned pos = atomicAdd(&s_pos, 1u);
                sbuf[pos] = my[j];
            }
        }
        __syncthreads();
    }

    // ---- rank + decode/scatter (no barriers; LDS broadcast reads) ----
    for (int i0 = 0; i0 < Meff; i0 += 1024) {
        int i = i0 + tid;
        if (i < Meff) {
            ull key = sbuf[i];
            int rank = 0;
            int j = 0;
            for (; j + 4 <= Meff; j += 4) {
                rank += (sbuf[j]     > key);
                rank += (sbuf[j + 1] > key);
                rank += (sbuf[j + 2] > key);
                rank += (sbuf[j + 3] > key);
            }
            for (; j < Meff; ++j) rank += (sbuf[j] > key);
            if (rank < nsel) {
                float sc = __uint_as_float((unsigned)(key >> 32));
                int idx = (int)(~(unsigned)key);
                // SSD decode, bit-identical to the reference expression (contract off)
                float l0 = loc[((size_t)b * 4 + 0) * P + idx];
                float l1 = loc[((size_t)b * 4 + 1) * P + idx];
                float l2 = loc[((size_t)b * 4 + 2) * P + idx];
                float l3 = loc[((size_t)b * 4 + 3) * P + idx];
                float4 pr4 = *(const float4*)(prior + (size_t)idx * 4);
                float cx = pr4.x + (l0 * 0.1f) * pr4.z;
                float cy = pr4.y + (l1 * 0.1f) * pr4.w;
                float w  = pr4.z * expf(l2 * 0.2f);
                float h  = pr4.w * expf(l3 * 0.2f);
                float x1 = cx - w / 2.f, y1 = cy - h / 2.f;
                float x2 = cx + w / 2.f, y2 = cy + h / 2.f;
                sx1[rank] = x1; sy1[rank] = y1; sx2[rank] = x2; sy2[rank] = y2;
                sar[rank] = fmaxf(x2 - x1, 0.f) * fmaxf(y2 - y1, 0.f);
                float* rr = &rowsL[rank * 5];
                rr[0] = sc; rr[1] = cx; rr[2] = cy; rr[3] = w; rr[4] = h;
            }
        }
    }
    __syncthreads();

    // ---- streaming greedy NMS over 64-rank chunks ----
    int nchunk = (nsel + 63) >> 6;
    for (int c = 0; c < nchunk; ++c) {
        int ib = (c << 6) + (wv << 2);       // 16 waves x 4 rows = 64 rows of chunk c
        float bx1[4], by1[4], bx2[4], by2[4], ba[4];
        #pragma unroll
        for (int r = 0; r < 4; ++r) {
            bx1[r] = sx1[ib + r]; by1[r] = sy1[ib + r];
            bx2[r] = sx2[ib + r]; by2[r] = sy2[ib + r]; ba[r] = sar[ib + r];
        }
        unsigned sup4 = 0u;
        for (int cp = 0; cp < c; ++cp) {     // vs previously-finalized kept boxes
            int j = (cp << 6) + lane;
            ull kb = keepw[cp];
            bool jk = ((kb >> lane) & 1ull) != 0ull;
            float jx1 = sx1[j], jy1 = sy1[j], jx2 = sx2[j], jy2 = sy2[j], ja = sar[j];
            #pragma unroll
            for (int r = 0; r < 4; ++r) {
                float ww = fmaxf(fminf(bx2[r], jx2) - fmaxf(bx1[r], jx1), 0.f);
                float hh = fmaxf(fminf(by2[r], jy2) - fmaxf(by1[r], jy1), 0.f);
                float inter = ww * hh;
                float uni = ba[r] + ja - inter;
                float iou = inter / fmaxf(uni, 1e-12f);
                if (__ballot(jk && (iou > nth)) != 0ull) sup4 |= (1u << r);
            }
        }
        {   // diagonal 64x64 block bits
            int j = (c << 6) + lane;
            float jx1 = sx1[j], jy1 = sy1[j], jx2 = sx2[j], jy2 = sy2[j], ja = sar[j];
            #pragma unroll
            for (int r = 0; r < 4; ++r) {
                float ww = fmaxf(fminf(bx2[r], jx2) - fmaxf(bx1[r], jx1), 0.f);
                float hh = fmaxf(fminf(by2[r], jy2) - fmaxf(by1[r], jy1), 0.f);
                float inter = ww * hh;
                float uni = ba[r] + ja - inter;
                float iou = inter / fmaxf(uni, 1e-12f);
                ull bits = __ballot(iou > nth);
                if (lane == 0) Dm[(wv << 2) + r] = bits;
            }
        }
        if (lane < 4) supArr[(wv << 2) + lane] = (sup4 >> lane) & 1u;
        __syncthreads();

        if (wv == 0) {                       // serial greedy on chunk c (all lanes redundant)
            unsigned sv = supArr[lane];
            ull P0 = __ballot(sv != 0u);
            int rem = nsel - (c << 6);       // >= 1 since c < nchunk
            ull valid = (rem >= 64) ? ~0ull : ((1ull << rem) - 1ull);
            ull cur = P0 | ~valid;           // invalid rows pre-suppressed
            ull dbuf[16], dnxt[16];
            #pragma unroll
            for (int k = 0; k < 16; ++k) dbuf[k] = Dm[k];
            #pragma unroll
            for (int grp = 0; grp < 4; ++grp) {
                if (grp < 3) {
                    #pragma unroll
                    for (int k = 0; k < 16; ++k) dnxt[k] = Dm[((grp + 1) << 4) + k];
                }
                #pragma unroll
                for (int k = 0; k < 16; ++k) {   // pure-VALU serial steps
                    int i2 = (grp << 4) + k;
                    ull supm = (ull)((long long)(cur << (63 - i2)) >> 63);
                    ull himask = (i2 == 63) ? 0ull : (~0ull << (i2 + 1));
                    cur |= dbuf[k] & himask & ~supm;
                }
                if (grp < 3) {
                    #pragma unroll
                    for (int k = 0; k < 16; ++k) dbuf[k] = dnxt[k];
                }
            }
            if (lane == 0) keepw[c] = (~cur) & valid;
        }
        __syncthreads();
    }

    // ---- pack ----
    if (tid == 0) {
        unsigned cacc = 0;
        for (int w2 = 0; w2 < WORDS; ++w2) { pref[w2] = cacc; cacc += (unsigned)__popcll(keepw[w2]); }
        pref[WORDS] = cacc;
    }
    __syncthreads();
    unsigned tot = pref[WORDS];
    float* obase = out + (size_t)bc * KTOP * 5;
    for (int r = tid; r < KTOP; r += 1024) {
        ull kv = keepw[r >> 6];
        if ((kv >> (r & 63)) & 1ull) {
            int pos = (int)pref[r >> 6] + __popcll(kv & ((1ull << (r & 63)) - 1ull));
            const float* rr = &rowsL[r * 5];
            float* oo = obase + pos * 5;
            oo[0] = rr[0]; oo[1] = rr[1]; oo[2] = rr[2]; oo[3] = rr[3]; oo[4] = rr[4];
        }
        if (r >= (int)tot) {                 // zero-fill tail
            float* oo = obase + r * 5;
            oo[0] = 0.f; oo[1] = 0.f; oo[2] = 0.f; oo[3] = 0.f; oo[4] = 0.f;
        }
    }
}

// ------------------------------- launcher -------------------------------
extern "C" void kernel_launch(void* const* d_in, const int* in_sizes, int n_in,
                              void* d_out, int out_size, void* d_ws, size_t ws_size,
                              hipStream_t stream) {
    (void)n_in; (void)out_size; (void)ws_size;
    const float* loc   = (const float*)d_in[0];
    const float* conf  = (const float*)d_in[1];
    const float* prior = (const float*)d_in[2];
    const float* cth   = (const float*)d_in[3];
    const float* nth   = (const float*)d_in[4];
    float* out = (float*)d_out;

    int P   = in_sizes[2] / 4;
    int B   = in_sizes[0] / (4 * P);
    int C   = in_sizes[1] / (B * P);
    int Cfg = C - 1;
    int NBC = B * Cfg;

    // ---- carve workspace (256B aligned sections; widest types first) ----
    char* base = (char*)d_ws;
    size_t off = 0;
    auto carve = [&](size_t bytes) { char* p = base + off; off = (off + bytes + 255) & ~(size_t)255; return p; };

    ull*      cand   = (ull*)     carve((size_t)NBC * CAP * 8);
    float*    scores = (float*)   carve((size_t)NBC * P * 4);
    unsigned* hist   = (unsigned*)carve((size_t)NBC * NB2 * 4 + (size_t)NBC * 4); // hist + cnt
    unsigned* cnt    = hist + (size_t)NBC * NB2;
    unsigned* pivot  = (unsigned*)carve((size_t)NBC * 4);

    int histW = NBC * NB2 + NBC;             // words to zero (hist + cnt)

    int GY = (P + GSTAGE - 1) / GSTAGE;      // gather chunks: chunk <= GSTAGE guaranteed
    if (GY < 32) GY = 32;

    int n1 = B * P;
    decode_kernel<<<(n1 + 255) / 256, 256, 0, stream>>>(conf, scores, hist, histW, B, C, P);
    hist_kernel<<<dim3(NBC, HCHUNK), 256, 0, stream>>>(scores, cth, hist, P);
    gather_kernel<<<dim3(NBC, GY), 256, 0, stream>>>(scores, hist, pivot, cnt, cand, cth, P);
    nms_kernel<<<NBC, 1024, 0, stream>>>(cand, cnt, pivot, loc, prior, nth, out, P, Cfg);
}